// Round 3
// baseline (607.325 us; speedup 1.0000x reference)
//
#include <hip/hip_runtime.h>
#include <math.h>

#define NV 100000
#define NE 3200000
#define NK 16
#define NT 4
#define NB 782            // ceil(NV/128) buckets of 128 nodes each
#define NG 8              // writer groups (blockIdx%8 ~ XCD heuristic)
#define NBG (NB * NG)     // 6256 counters
#define PI_F 3.14159265358979323846f

// ---------------- fallback path (R1 atomic kernel) ----------------

__global__ __launch_bounds__(256) void zero_out_kernel(float4* __restrict__ out, int n4) {
    int i = blockIdx.x * blockDim.x + threadIdx.x;
    if (i < n4) out[i] = make_float4(0.f, 0.f, 0.f, 0.f);
}

__global__ __launch_bounds__(256) void atomic_conv_edge_kernel(
    const float* __restrict__ feat, const float* __restrict__ dist,
    const int* __restrict__ src, const int* __restrict__ dst,
    const float* __restrict__ cutoffs, const float* __restrict__ means,
    const float* __restrict__ scaling, const float* __restrict__ feats_use,
    float* __restrict__ out)
{
    int e = blockIdx.x * blockDim.x + threadIdx.x;
    if (e >= NE) return;
    float d = dist[e];
    int s = src[e];
    int v = dst[e];
    float fv = feat[s];
    int ty = 0;
#pragma unroll
    for (int t = 1; t < NT; ++t) if (fv == feats_use[t]) ty = t;
    float* o = out + (size_t)v * (NT * NK) + (size_t)ty * NK;
#pragma unroll
    for (int k = 0; k < NK; ++k) {
        float c = cutoffs[k], m = means[k], sc = scaling[k];
        float dm = d - m;
        float rbf = __expf(-sc * dm * dm);
        float cosv = 0.5f * (__cosf(PI_F * d / c) + 1.0f);
        float he = (d <= c) ? rbf * cosv : 0.0f;
        __hip_atomic_fetch_add(o + k, he, __ATOMIC_RELAXED, __HIP_MEMORY_SCOPE_AGENT);
    }
}

// ---------------- bucket-sort + LDS-tile reduce path ----------------

__global__ __launch_bounds__(256) void zero_counts_kernel(int* __restrict__ p, int n) {
    int i = blockIdx.x * blockDim.x + threadIdx.x;
    if (i < n) p[i] = 0;
}

// per-block LDS histogram over NB buckets, flushed to counts[bucket*NG + g]
__global__ __launch_bounds__(256) void hist_kernel(const int4* __restrict__ dst4,
                                                   int* __restrict__ counts) {
    __shared__ int h[NB];
    for (int i = threadIdx.x; i < NB; i += 256) h[i] = 0;
    __syncthreads();
    const int nq = NE / 4;
    for (int q = blockIdx.x * 256 + threadIdx.x; q < nq; q += gridDim.x * 256) {
        int4 v = dst4[q];
        atomicAdd(&h[v.x >> 7], 1);
        atomicAdd(&h[v.y >> 7], 1);
        atomicAdd(&h[v.z >> 7], 1);
        atomicAdd(&h[v.w >> 7], 1);
    }
    __syncthreads();
    int g = blockIdx.x & (NG - 1);
    for (int i = threadIdx.x; i < NB; i += 256) {
        int c = h[i];
        if (c) atomicAdd(&counts[i * NG + g], c);
    }
}

// single-block exclusive scan of NBG counters -> offsets + cursors
__global__ __launch_bounds__(1024) void scan_kernel(const int* __restrict__ counts,
                                                    int* __restrict__ offsets,
                                                    int* __restrict__ cursors) {
    __shared__ int s[1024];
    const int CH = (NBG + 1023) / 1024;  // 7
    int t = threadIdx.x;
    int base = t * CH;
    int loc[CH];
    int sum = 0;
#pragma unroll
    for (int i = 0; i < CH; ++i) {
        int idx = base + i;
        int v = (idx < NBG) ? counts[idx] : 0;
        loc[i] = sum;
        sum += v;
    }
    s[t] = sum;
    __syncthreads();
#pragma unroll
    for (int off = 1; off < 1024; off <<= 1) {
        int v = (t >= off) ? s[t - off] : 0;
        __syncthreads();
        s[t] += v;
        __syncthreads();
    }
    int excl = (t > 0) ? s[t - 1] : 0;
#pragma unroll
    for (int i = 0; i < CH; ++i) {
        int idx = base + i;
        if (idx < NBG) {
            int o = excl + loc[i];
            offsets[idx] = o;
            cursors[idx] = o;
        }
    }
    if (t == 1023) offsets[NBG] = NE;
}

__device__ __forceinline__ void scatter_one(float d, int s, int v, int g,
                                            float f1, float f2, float f3,
                                            const float* __restrict__ feat,
                                            int* __restrict__ cursors,
                                            unsigned* __restrict__ payload) {
    float fv = feat[s];
    int ty = (fv == f1) ? 1 : (fv == f2) ? 2 : (fv == f3) ? 3 : 0;
    int b = v >> 7;
    int ldst = v & 127;
    // [31:9]=top 23 bits of d | [8:7]=ty | [6:0]=ldst
    unsigned packed = (__float_as_uint(d) & 0xFFFFFE00u) | ((unsigned)ty << 7) | (unsigned)ldst;
    int pos = __hip_atomic_fetch_add(&cursors[b * NG + g], 1,
                                     __ATOMIC_RELAXED, __HIP_MEMORY_SCOPE_AGENT);
    payload[pos] = packed;
}

__global__ __launch_bounds__(256) void scatter_kernel(
    const float* __restrict__ feat, const float4* __restrict__ dist4,
    const int4* __restrict__ src4, const int4* __restrict__ dst4,
    const float* __restrict__ feats_use,
    int* __restrict__ cursors, unsigned* __restrict__ payload) {
    float f1 = feats_use[1], f2 = feats_use[2], f3 = feats_use[3];
    int g = blockIdx.x & (NG - 1);
    const int nq = NE / 4;
    for (int q = blockIdx.x * 256 + threadIdx.x; q < nq; q += gridDim.x * 256) {
        float4 dv = dist4[q];
        int4 sv = src4[q];
        int4 tv = dst4[q];
        scatter_one(dv.x, sv.x, tv.x, g, f1, f2, f3, feat, cursors, payload);
        scatter_one(dv.y, sv.y, tv.y, g, f1, f2, f3, feat, cursors, payload);
        scatter_one(dv.z, sv.z, tv.z, g, f1, f2, f3, feat, cursors, payload);
        scatter_one(dv.w, sv.w, tv.w, g, f1, f2, f3, feat, cursors, payload);
    }
}

// one block per bucket: accumulate into padded LDS tile, write out coalesced
__global__ __launch_bounds__(256) void reduce_kernel(
    const unsigned* __restrict__ payload, const int* __restrict__ offsets,
    const float* __restrict__ cutoffs, const float* __restrict__ means,
    const float* __restrict__ scaling, float* __restrict__ out) {
    __shared__ float tile[128 * 65];
    int b = blockIdx.x;
    for (int i = threadIdx.x; i < 128 * 65; i += 256) tile[i] = 0.f;

    float m_[NK], sc_[NK], c_[NK];
#pragma unroll
    for (int k = 0; k < NK; ++k) {
        m_[k] = means[k];
        sc_[k] = scaling[k];
        c_[k] = cutoffs[k];
    }
    __syncthreads();

    int s0 = offsets[b * NG];
    int s1 = offsets[(b + 1) * NG];  // b==NB-1 reads offsets[NBG]==NE
    for (int i = s0 + threadIdx.x; i < s1; i += 256) {
        unsigned p = payload[i];
        float d = __uint_as_float(p & 0xFFFFFE00u);
        int ty = (p >> 7) & 3;
        int ldst = p & 127;
        float* o = &tile[ldst * 65 + ty * 16];
#pragma unroll
        for (int k = 0; k < NK; ++k) {
            float dm = d - m_[k];
            float rbf = __expf(-sc_[k] * dm * dm);
            float cosv = 0.5f * (__cosf(PI_F * d / c_[k]) + 1.0f);
            float he = (d <= c_[k]) ? rbf * cosv : 0.0f;
            atomicAdd(o + k, he);
        }
    }
    __syncthreads();

    int nodeBase = b * 128;
    int nrows = NV - nodeBase;
    if (nrows > 128) nrows = 128;
    for (int i = threadIdx.x; i < nrows * 64; i += 256) {
        int r = i >> 6;
        int c = i & 63;
        out[(size_t)(nodeBase + r) * 64 + c] = tile[r * 65 + c];
    }
}

extern "C" void kernel_launch(void* const* d_in, const int* in_sizes, int n_in,
                              void* d_out, int out_size, void* d_ws, size_t ws_size,
                              hipStream_t stream) {
    const float* feat      = (const float*)d_in[0];
    const float* dist      = (const float*)d_in[1];
    const int*   src       = (const int*)d_in[2];
    const int*   dst       = (const int*)d_in[3];
    const float* cutoffs   = (const float*)d_in[4];
    const float* means     = (const float*)d_in[5];
    const float* scaling   = (const float*)d_in[6];
    const float* feats_use = (const float*)d_in[7];
    float* out = (float*)d_out;

    size_t off = 0;
    auto alloc = [&](size_t bytes) {
        size_t cur = off;
        off = (off + bytes + 255) & ~(size_t)255;
        return cur;
    };
    size_t o_counts  = alloc((size_t)NBG * 4);
    size_t o_offsets = alloc((size_t)(NBG + 1) * 4);
    size_t o_cursors = alloc((size_t)NBG * 4);
    size_t o_payload = alloc((size_t)NE * 4);
    size_t needed = off;

    if (ws_size < needed) {
        int n4 = out_size / 4;
        zero_out_kernel<<<(n4 + 255) / 256, 256, 0, stream>>>((float4*)out, n4);
        atomic_conv_edge_kernel<<<(NE + 255) / 256, 256, 0, stream>>>(
            feat, dist, src, dst, cutoffs, means, scaling, feats_use, out);
        return;
    }

    char* ws = (char*)d_ws;
    int* counts  = (int*)(ws + o_counts);
    int* offsets = (int*)(ws + o_offsets);
    int* cursors = (int*)(ws + o_cursors);
    unsigned* payload = (unsigned*)(ws + o_payload);

    zero_counts_kernel<<<(NBG + 255) / 256, 256, 0, stream>>>(counts, NBG);

    hist_kernel<<<256, 256, 0, stream>>>((const int4*)dst, counts);

    scan_kernel<<<1, 1024, 0, stream>>>(counts, offsets, cursors);

    scatter_kernel<<<1024, 256, 0, stream>>>(
        feat, (const float4*)dist, (const int4*)src, (const int4*)dst,
        feats_use, cursors, payload);

    reduce_kernel<<<NB, 256, 0, stream>>>(
        payload, offsets, cutoffs, means, scaling, out);
}

// Round 4
// 331.216 us; speedup vs baseline: 1.8336x; 1.8336x over previous
//
#include <hip/hip_runtime.h>
#include <math.h>

#define NV 100000
#define NE 3200000
#define NK 16
#define NT 4
#define NB 782            // ceil(NV/128) buckets of 128 nodes each
#define NG 8              // writer groups (blockIdx%8 ~ XCD heuristic)
#define NBG (NB * NG)     // 6256 counters
#define BCAP 6016         // reduce chunk capacity (edges)
#define PI_F 3.14159265358979323846f

// ---------------- fallback path (R1 atomic kernel) ----------------

__global__ __launch_bounds__(256) void zero_out_kernel(float4* __restrict__ out, int n4) {
    int i = blockIdx.x * blockDim.x + threadIdx.x;
    if (i < n4) out[i] = make_float4(0.f, 0.f, 0.f, 0.f);
}

__global__ __launch_bounds__(256) void atomic_conv_edge_kernel(
    const float* __restrict__ feat, const float* __restrict__ dist,
    const int* __restrict__ src, const int* __restrict__ dst,
    const float* __restrict__ cutoffs, const float* __restrict__ means,
    const float* __restrict__ scaling, const float* __restrict__ feats_use,
    float* __restrict__ out)
{
    int e = blockIdx.x * blockDim.x + threadIdx.x;
    if (e >= NE) return;
    float d = dist[e];
    int s = src[e];
    int v = dst[e];
    float fv = feat[s];
    int ty = 0;
#pragma unroll
    for (int t = 1; t < NT; ++t) if (fv == feats_use[t]) ty = t;
    float* o = out + (size_t)v * (NT * NK) + (size_t)ty * NK;
#pragma unroll
    for (int k = 0; k < NK; ++k) {
        float c = cutoffs[k], m = means[k], sc = scaling[k];
        float dm = d - m;
        float rbf = __expf(-sc * dm * dm);
        float cosv = 0.5f * (__cosf(PI_F * d / c) + 1.0f);
        float he = (d <= c) ? rbf * cosv : 0.0f;
        __hip_atomic_fetch_add(o + k, he, __ATOMIC_RELAXED, __HIP_MEMORY_SCOPE_AGENT);
    }
}

// ---------------- bucket-sort + owner-compute reduce path ----------------

__global__ __launch_bounds__(256) void zero_counts_kernel(int* __restrict__ p, int n) {
    int i = blockIdx.x * blockDim.x + threadIdx.x;
    if (i < n) p[i] = 0;
}

__global__ __launch_bounds__(256) void hist_kernel(const int4* __restrict__ dst4,
                                                   int* __restrict__ counts) {
    __shared__ int h[NB];
    for (int i = threadIdx.x; i < NB; i += 256) h[i] = 0;
    __syncthreads();
    const int nq = NE / 4;
    for (int q = blockIdx.x * 256 + threadIdx.x; q < nq; q += gridDim.x * 256) {
        int4 v = dst4[q];
        atomicAdd(&h[v.x >> 7], 1);
        atomicAdd(&h[v.y >> 7], 1);
        atomicAdd(&h[v.z >> 7], 1);
        atomicAdd(&h[v.w >> 7], 1);
    }
    __syncthreads();
    int g = blockIdx.x & (NG - 1);
    for (int i = threadIdx.x; i < NB; i += 256) {
        int c = h[i];
        if (c) atomicAdd(&counts[i * NG + g], c);
    }
}

__global__ __launch_bounds__(1024) void scan_kernel(const int* __restrict__ counts,
                                                    int* __restrict__ offsets,
                                                    int* __restrict__ cursors) {
    __shared__ int s[1024];
    const int CH = (NBG + 1023) / 1024;  // 7
    int t = threadIdx.x;
    int base = t * CH;
    int loc[CH];
    int sum = 0;
#pragma unroll
    for (int i = 0; i < CH; ++i) {
        int idx = base + i;
        int v = (idx < NBG) ? counts[idx] : 0;
        loc[i] = sum;
        sum += v;
    }
    s[t] = sum;
    __syncthreads();
#pragma unroll
    for (int off = 1; off < 1024; off <<= 1) {
        int v = (t >= off) ? s[t - off] : 0;
        __syncthreads();
        s[t] += v;
        __syncthreads();
    }
    int excl = (t > 0) ? s[t - 1] : 0;
#pragma unroll
    for (int i = 0; i < CH; ++i) {
        int idx = base + i;
        if (idx < NBG) {
            int o = excl + loc[i];
            offsets[idx] = o;
            cursors[idx] = o;
        }
    }
    if (t == 1023) offsets[NBG] = NE;
}

__device__ __forceinline__ void scatter_one(float d, int s, int v, int g,
                                            float f1, float f2, float f3,
                                            const float* __restrict__ feat,
                                            int* __restrict__ cursors,
                                            unsigned* __restrict__ payload) {
    float fv = feat[s];
    int ty = (fv == f1) ? 1 : (fv == f2) ? 2 : (fv == f3) ? 3 : 0;
    int b = v >> 7;
    int ldst = v & 127;
    // [31:9]=top 23 bits of d | [8:7]=ty | [6:0]=ldst
    unsigned packed = (__float_as_uint(d) & 0xFFFFFE00u) | ((unsigned)ty << 7) | (unsigned)ldst;
    int pos = __hip_atomic_fetch_add(&cursors[b * NG + g], 1,
                                     __ATOMIC_RELAXED, __HIP_MEMORY_SCOPE_AGENT);
    payload[pos] = packed;
}

__global__ __launch_bounds__(256) void scatter_kernel(
    const float* __restrict__ feat, const float4* __restrict__ dist4,
    const int4* __restrict__ src4, const int4* __restrict__ dst4,
    const float* __restrict__ feats_use,
    int* __restrict__ cursors, unsigned* __restrict__ payload) {
    float f1 = feats_use[1], f2 = feats_use[2], f3 = feats_use[3];
    int g = blockIdx.x & (NG - 1);
    const int nq = NE / 4;
    for (int q = blockIdx.x * 256 + threadIdx.x; q < nq; q += gridDim.x * 256) {
        float4 dv = dist4[q];
        int4 sv = src4[q];
        int4 tv = dst4[q];
        scatter_one(dv.x, sv.x, tv.x, g, f1, f2, f3, feat, cursors, payload);
        scatter_one(dv.y, sv.y, tv.y, g, f1, f2, f3, feat, cursors, payload);
        scatter_one(dv.z, sv.z, tv.z, g, f1, f2, f3, feat, cursors, payload);
        scatter_one(dv.w, sv.w, tv.w, g, f1, f2, f3, feat, cursors, payload);
    }
}

// one block per bucket: LDS counting sort by key=(ldst<<1)|ty_half, then
// thread t owns key t -> register accumulation, no atomics in hot loop.
__global__ __launch_bounds__(256, 3) void reduce_kernel(
    const unsigned* __restrict__ payload, const int* __restrict__ offsets,
    const float* __restrict__ cutoffs, const float* __restrict__ means,
    const float* __restrict__ scaling, float* __restrict__ out)
{
    __shared__ unsigned raw[BCAP];
    __shared__ unsigned srt[BCAP];
    __shared__ int scn[256];
    __shared__ int cur[256];
    __shared__ int coff[257];

    int b = blockIdx.x;
    int t = threadIdx.x;
    int s0 = offsets[b * NG];
    int s1 = offsets[(b + 1) * NG];

    float m_[NK], nsc_[NK], c_[NK], w_[NK];
#pragma unroll
    for (int k = 0; k < NK; ++k) {
        m_[k] = means[k];
        nsc_[k] = -scaling[k];
        c_[k] = cutoffs[k];
        w_[k] = PI_F / cutoffs[k];
    }

    float accA[NK], accB[NK];
#pragma unroll
    for (int k = 0; k < NK; ++k) { accA[k] = 0.f; accB[k] = 0.f; }

    for (int base = s0; base < s1; base += BCAP) {
        int n = s1 - base;
        if (n > BCAP) n = BCAP;

        for (int i = t; i < n; i += 256) raw[i] = payload[base + i];
        scn[t] = 0;
        __syncthreads();

        for (int i = t; i < n; i += 256) {
            unsigned p = raw[i];
            int key = ((p & 127) << 1) | ((p >> 8) & 1);
            atomicAdd(&scn[key], 1);
        }
        __syncthreads();

        int x = scn[t];
#pragma unroll
        for (int off2 = 1; off2 < 256; off2 <<= 1) {
            int v = (t >= off2) ? scn[t - off2] : 0;
            __syncthreads();
            scn[t] += v;
            __syncthreads();
        }
        int excl = scn[t] - x;
        coff[t] = excl;
        cur[t] = excl;
        if (t == 0) coff[256] = n;
        __syncthreads();

        for (int i = t; i < n; i += 256) {
            unsigned p = raw[i];
            int key = ((p & 127) << 1) | ((p >> 8) & 1);
            int pos = atomicAdd(&cur[key], 1);
            srt[pos] = p;
        }
        __syncthreads();

        int e0 = coff[t];
        int e1 = coff[t + 1];
        for (int i = e0; i < e1; ++i) {
            unsigned p = srt[i];
            float d = __uint_as_float(p & 0xFFFFFE00u);
            int typar = (p >> 7) & 1;
            float he[NK];
#pragma unroll
            for (int k = 0; k < NK; ++k) {
                float dm = d - m_[k];
                float rbf = __expf(nsc_[k] * dm * dm);
                float cosv = 0.5f * (__cosf(w_[k] * d) + 1.0f);
                he[k] = (d <= c_[k]) ? rbf * cosv : 0.0f;
            }
            if (typar == 0) {
#pragma unroll
                for (int k = 0; k < NK; ++k) accA[k] += he[k];
            } else {
#pragma unroll
                for (int k = 0; k < NK; ++k) accB[k] += he[k];
            }
        }
        __syncthreads();
    }

    int node = b * 128 + (t >> 1);
    if (node < NV) {
        int h = t & 1;
        // ty = 2h -> cols h*32..+15 (accA); ty = 2h+1 -> cols h*32+16..+31 (accB)
        float4* o = (float4*)(out + (size_t)node * 64 + h * 32);
#pragma unroll
        for (int k = 0; k < 4; ++k)
            o[k] = make_float4(accA[4 * k], accA[4 * k + 1], accA[4 * k + 2], accA[4 * k + 3]);
#pragma unroll
        for (int k = 0; k < 4; ++k)
            o[4 + k] = make_float4(accB[4 * k], accB[4 * k + 1], accB[4 * k + 2], accB[4 * k + 3]);
    }
}

extern "C" void kernel_launch(void* const* d_in, const int* in_sizes, int n_in,
                              void* d_out, int out_size, void* d_ws, size_t ws_size,
                              hipStream_t stream) {
    const float* feat      = (const float*)d_in[0];
    const float* dist      = (const float*)d_in[1];
    const int*   src       = (const int*)d_in[2];
    const int*   dst       = (const int*)d_in[3];
    const float* cutoffs   = (const float*)d_in[4];
    const float* means     = (const float*)d_in[5];
    const float* scaling   = (const float*)d_in[6];
    const float* feats_use = (const float*)d_in[7];
    float* out = (float*)d_out;

    size_t off = 0;
    auto alloc = [&](size_t bytes) {
        size_t cur = off;
        off = (off + bytes + 255) & ~(size_t)255;
        return cur;
    };
    size_t o_counts  = alloc((size_t)NBG * 4);
    size_t o_offsets = alloc((size_t)(NBG + 1) * 4);
    size_t o_cursors = alloc((size_t)NBG * 4);
    size_t o_payload = alloc((size_t)NE * 4);
    size_t needed = off;

    if (ws_size < needed) {
        int n4 = out_size / 4;
        zero_out_kernel<<<(n4 + 255) / 256, 256, 0, stream>>>((float4*)out, n4);
        atomic_conv_edge_kernel<<<(NE + 255) / 256, 256, 0, stream>>>(
            feat, dist, src, dst, cutoffs, means, scaling, feats_use, out);
        return;
    }

    char* ws = (char*)d_ws;
    int* counts  = (int*)(ws + o_counts);
    int* offsets = (int*)(ws + o_offsets);
    int* cursors = (int*)(ws + o_cursors);
    unsigned* payload = (unsigned*)(ws + o_payload);

    zero_counts_kernel<<<(NBG + 255) / 256, 256, 0, stream>>>(counts, NBG);

    hist_kernel<<<256, 256, 0, stream>>>((const int4*)dst, counts);

    scan_kernel<<<1, 1024, 0, stream>>>(counts, offsets, cursors);

    scatter_kernel<<<1024, 256, 0, stream>>>(
        feat, (const float4*)dist, (const int4*)src, (const int4*)dst,
        feats_use, cursors, payload);

    reduce_kernel<<<NB, 256, 0, stream>>>(
        payload, offsets, cutoffs, means, scaling, out);
}

// Round 6
// 223.044 us; speedup vs baseline: 2.7229x; 1.4850x over previous
//
#include <hip/hip_runtime.h>
#include <math.h>

#define NV 100000
#define NE 3200000
#define NK 16
#define NT 4
#define NB 782            // ceil(NV/128) buckets of 128 nodes each
#define NG 8              // writer groups (blockIdx%8 ~ XCD heuristic)
#define NBG (NB * NG)     // 6256 counters
#define BCAP 6016         // reduce chunk capacity (edges)
#define SCH 8192          // scatter chunk (edges per block)
#define NCHUNK ((NE + SCH - 1) / SCH)  // 391
#define PI_F 3.14159265358979323846f

// ---------------- fallback path (R1 atomic kernel) ----------------

__global__ __launch_bounds__(256) void zero_out_kernel(float4* __restrict__ out, int n4) {
    int i = blockIdx.x * blockDim.x + threadIdx.x;
    if (i < n4) out[i] = make_float4(0.f, 0.f, 0.f, 0.f);
}

__global__ __launch_bounds__(256) void atomic_conv_edge_kernel(
    const float* __restrict__ feat, const float* __restrict__ dist,
    const int* __restrict__ src, const int* __restrict__ dst,
    const float* __restrict__ cutoffs, const float* __restrict__ means,
    const float* __restrict__ scaling, const float* __restrict__ feats_use,
    float* __restrict__ out)
{
    int e = blockIdx.x * blockDim.x + threadIdx.x;
    if (e >= NE) return;
    float d = dist[e];
    int s = src[e];
    int v = dst[e];
    float fv = feat[s];
    int ty = 0;
#pragma unroll
    for (int t = 1; t < NT; ++t) if (fv == feats_use[t]) ty = t;
    float* o = out + (size_t)v * (NT * NK) + (size_t)ty * NK;
#pragma unroll
    for (int k = 0; k < NK; ++k) {
        float c = cutoffs[k], m = means[k], sc = scaling[k];
        float dm = d - m;
        float rbf = __expf(-sc * dm * dm);
        float cosv = 0.5f * (__cosf(PI_F * d / c) + 1.0f);
        float he = (d <= c) ? rbf * cosv : 0.0f;
        __hip_atomic_fetch_add(o + k, he, __ATOMIC_RELAXED, __HIP_MEMORY_SCOPE_AGENT);
    }
}

// ---------------- bucket-sort + owner-compute reduce path ----------------

__global__ __launch_bounds__(256) void zero_counts_kernel(int* __restrict__ p, int n) {
    int i = blockIdx.x * blockDim.x + threadIdx.x;
    if (i < n) p[i] = 0;
}

// per-chunk histogram with the EXACT same chunk->group mapping as scatter_kernel:
// chunk c covers edges [c*SCH, c*SCH+SCH), group g = c & 7.
__global__ __launch_bounds__(256) void hist_kernel(const int4* __restrict__ dst4,
                                                   int* __restrict__ counts) {
    __shared__ int h[NB];
    for (int i = threadIdx.x; i < NB; i += 256) h[i] = 0;
    __syncthreads();
    const int nqTot = NE / 4;                 // 800000 quads
    int q0 = blockIdx.x * (SCH / 4);          // 2048 quads per chunk
    int nq = nqTot - q0;
    if (nq > SCH / 4) nq = SCH / 4;
    for (int i = threadIdx.x; i < nq; i += 256) {
        int4 v = dst4[q0 + i];
        atomicAdd(&h[v.x >> 7], 1);
        atomicAdd(&h[v.y >> 7], 1);
        atomicAdd(&h[v.z >> 7], 1);
        atomicAdd(&h[v.w >> 7], 1);
    }
    __syncthreads();
    int g = blockIdx.x & (NG - 1);
    for (int i = threadIdx.x; i < NB; i += 256) {
        int c = h[i];
        if (c) atomicAdd(&counts[i * NG + g], c);
    }
}

__global__ __launch_bounds__(1024) void scan_kernel(const int* __restrict__ counts,
                                                    int* __restrict__ offsets,
                                                    int* __restrict__ cursors) {
    __shared__ int s[1024];
    const int CH = (NBG + 1023) / 1024;  // 7
    int t = threadIdx.x;
    int base = t * CH;
    int loc[CH];
    int sum = 0;
#pragma unroll
    for (int i = 0; i < CH; ++i) {
        int idx = base + i;
        int v = (idx < NBG) ? counts[idx] : 0;
        loc[i] = sum;
        sum += v;
    }
    s[t] = sum;
    __syncthreads();
#pragma unroll
    for (int off = 1; off < 1024; off <<= 1) {
        int v = (t >= off) ? s[t - off] : 0;
        __syncthreads();
        s[t] += v;
        __syncthreads();
    }
    int excl = (t > 0) ? s[t - 1] : 0;
#pragma unroll
    for (int i = 0; i < CH; ++i) {
        int idx = base + i;
        if (idx < NBG) {
            int o = excl + loc[i];
            offsets[idx] = o;
            cursors[idx] = o;
        }
    }
    if (t == 1023) offsets[NBG] = NE;
}

// block-aggregated scatter: one cursor atomic per (bucket, block) instead of per edge.
// chunk c covers edges [c*SCH, c*SCH+SCH), group g = c & 7 — MUST match hist_kernel.
__global__ __launch_bounds__(256) void scatter_kernel(
    const float* __restrict__ feat, const float* __restrict__ dist,
    const int* __restrict__ src, const int* __restrict__ dst,
    const float* __restrict__ feats_use,
    int* __restrict__ cursors, unsigned* __restrict__ payload)
{
    __shared__ unsigned pld[SCH];
    __shared__ unsigned short bkt[SCH];
    __shared__ int hist[NB];
    __shared__ int base[NB];

    int t = threadIdx.x;
    int g = blockIdx.x & (NG - 1);
    int chunkBase = blockIdx.x * SCH;
    int n = NE - chunkBase;
    if (n > SCH) n = SCH;

    float f1 = feats_use[1], f2 = feats_use[2], f3 = feats_use[3];

    for (int i = t; i < NB; i += 256) hist[i] = 0;
    __syncthreads();

    for (int i = t; i < n; i += 256) {
        int e = chunkBase + i;
        float d = dist[e];
        int s = src[e];
        int v = dst[e];
        float fv = feat[s];
        int ty = (fv == f1) ? 1 : (fv == f2) ? 2 : (fv == f3) ? 3 : 0;
        int b = v >> 7;
        // [31:9]=top 23 bits of d | [8:7]=ty | [6:0]=ldst
        unsigned packed = (__float_as_uint(d) & 0xFFFFFE00u) |
                          ((unsigned)ty << 7) | (unsigned)(v & 127);
        pld[i] = packed;
        bkt[i] = (unsigned short)b;
        atomicAdd(&hist[b], 1);
    }
    __syncthreads();

    for (int i = t; i < NB; i += 256) {
        int c = hist[i];
        base[i] = c ? __hip_atomic_fetch_add(&cursors[i * NG + g], c,
                                             __ATOMIC_RELAXED, __HIP_MEMORY_SCOPE_AGENT)
                    : 0;
        hist[i] = 0;  // reuse as block-local cursor
    }
    __syncthreads();

    for (int i = t; i < n; i += 256) {
        int b = bkt[i];
        int lp = atomicAdd(&hist[b], 1);
        payload[base[b] + lp] = pld[i];
    }
}

// one block per bucket: LDS counting sort by key=(ldst<<1)|ty_half, then
// thread t owns key t -> register accumulation, no atomics in hot loop.
__global__ __launch_bounds__(256, 3) void reduce_kernel(
    const unsigned* __restrict__ payload, const int* __restrict__ offsets,
    const float* __restrict__ cutoffs, const float* __restrict__ means,
    const float* __restrict__ scaling, float* __restrict__ out)
{
    __shared__ unsigned raw[BCAP];
    __shared__ unsigned srt[BCAP];
    __shared__ int scn[256];
    __shared__ int cur[256];
    __shared__ int coff[257];

    int b = blockIdx.x;
    int t = threadIdx.x;
    int s0 = offsets[b * NG];
    int s1 = offsets[(b + 1) * NG];

    float m_[NK], nsc_[NK], c_[NK], w_[NK];
#pragma unroll
    for (int k = 0; k < NK; ++k) {
        m_[k] = means[k];
        nsc_[k] = -scaling[k];
        c_[k] = cutoffs[k];
        w_[k] = PI_F / cutoffs[k];
    }

    float accA[NK], accB[NK];
#pragma unroll
    for (int k = 0; k < NK; ++k) { accA[k] = 0.f; accB[k] = 0.f; }

    for (int base = s0; base < s1; base += BCAP) {
        int n = s1 - base;
        if (n > BCAP) n = BCAP;

        for (int i = t; i < n; i += 256) raw[i] = payload[base + i];
        scn[t] = 0;
        __syncthreads();

        for (int i = t; i < n; i += 256) {
            unsigned p = raw[i];
            int key = ((p & 127) << 1) | ((p >> 8) & 1);
            atomicAdd(&scn[key], 1);
        }
        __syncthreads();

        int x = scn[t];
#pragma unroll
        for (int off2 = 1; off2 < 256; off2 <<= 1) {
            int v = (t >= off2) ? scn[t - off2] : 0;
            __syncthreads();
            scn[t] += v;
            __syncthreads();
        }
        int excl = scn[t] - x;
        coff[t] = excl;
        cur[t] = excl;
        if (t == 0) coff[256] = n;
        __syncthreads();

        for (int i = t; i < n; i += 256) {
            unsigned p = raw[i];
            int key = ((p & 127) << 1) | ((p >> 8) & 1);
            int pos = atomicAdd(&cur[key], 1);
            srt[pos] = p;
        }
        __syncthreads();

        int e0 = coff[t];
        int e1 = coff[t + 1];
        for (int i = e0; i < e1; ++i) {
            unsigned p = srt[i];
            float d = __uint_as_float(p & 0xFFFFFE00u);
            int typar = (p >> 7) & 1;
            float he[NK];
#pragma unroll
            for (int k = 0; k < NK; ++k) {
                float dm = d - m_[k];
                float rbf = __expf(nsc_[k] * dm * dm);
                float cosv = 0.5f * (__cosf(w_[k] * d) + 1.0f);
                he[k] = (d <= c_[k]) ? rbf * cosv : 0.0f;
            }
            if (typar == 0) {
#pragma unroll
                for (int k = 0; k < NK; ++k) accA[k] += he[k];
            } else {
#pragma unroll
                for (int k = 0; k < NK; ++k) accB[k] += he[k];
            }
        }
        __syncthreads();
    }

    int node = b * 128 + (t >> 1);
    if (node < NV) {
        int h = t & 1;
        float4* o = (float4*)(out + (size_t)node * 64 + h * 32);
#pragma unroll
        for (int k = 0; k < 4; ++k)
            o[k] = make_float4(accA[4 * k], accA[4 * k + 1], accA[4 * k + 2], accA[4 * k + 3]);
#pragma unroll
        for (int k = 0; k < 4; ++k)
            o[4 + k] = make_float4(accB[4 * k], accB[4 * k + 1], accB[4 * k + 2], accB[4 * k + 3]);
    }
}

extern "C" void kernel_launch(void* const* d_in, const int* in_sizes, int n_in,
                              void* d_out, int out_size, void* d_ws, size_t ws_size,
                              hipStream_t stream) {
    const float* feat      = (const float*)d_in[0];
    const float* dist      = (const float*)d_in[1];
    const int*   src       = (const int*)d_in[2];
    const int*   dst       = (const int*)d_in[3];
    const float* cutoffs   = (const float*)d_in[4];
    const float* means     = (const float*)d_in[5];
    const float* scaling   = (const float*)d_in[6];
    const float* feats_use = (const float*)d_in[7];
    float* out = (float*)d_out;

    size_t off = 0;
    auto alloc = [&](size_t bytes) {
        size_t cur = off;
        off = (off + bytes + 255) & ~(size_t)255;
        return cur;
    };
    size_t o_counts  = alloc((size_t)NBG * 4);
    size_t o_offsets = alloc((size_t)(NBG + 1) * 4);
    size_t o_cursors = alloc((size_t)NBG * 4);
    size_t o_payload = alloc((size_t)NE * 4);
    size_t needed = off;

    if (ws_size < needed) {
        int n4 = out_size / 4;
        zero_out_kernel<<<(n4 + 255) / 256, 256, 0, stream>>>((float4*)out, n4);
        atomic_conv_edge_kernel<<<(NE + 255) / 256, 256, 0, stream>>>(
            feat, dist, src, dst, cutoffs, means, scaling, feats_use, out);
        return;
    }

    char* ws = (char*)d_ws;
    int* counts  = (int*)(ws + o_counts);
    int* offsets = (int*)(ws + o_offsets);
    int* cursors = (int*)(ws + o_cursors);
    unsigned* payload = (unsigned*)(ws + o_payload);

    zero_counts_kernel<<<(NBG + 255) / 256, 256, 0, stream>>>(counts, NBG);

    hist_kernel<<<NCHUNK, 256, 0, stream>>>((const int4*)dst, counts);

    scan_kernel<<<1, 1024, 0, stream>>>(counts, offsets, cursors);

    scatter_kernel<<<NCHUNK, 256, 0, stream>>>(
        feat, dist, src, dst, feats_use, cursors, payload);

    reduce_kernel<<<NB, 256, 0, stream>>>(
        payload, offsets, cutoffs, means, scaling, out);
}

// Round 8
// 213.258 us; speedup vs baseline: 2.8478x; 1.0459x over previous
//
#include <hip/hip_runtime.h>
#include <math.h>

#define NV 100000
#define NE 3200000
#define NK 16
#define NT 4
#define NB 782            // ceil(NV/128) buckets of 128 nodes each
#define NG 8              // writer groups (blockIdx%8 ~ XCD heuristic)
#define NBG (NB * NG)     // 6256 counters
#define BCAP 6016         // reduce chunk capacity (R6-proven: 51.7 KB LDS, 3 blocks/CU)
#define SCH 8192          // scatter chunk (edges per block)
#define NCHUNK ((NE + SCH - 1) / SCH)  // 391
#define PI_F 3.14159265358979323846f
#define LOG2E_F 1.4426950408889634f

// ---------------- fallback path (R1 atomic kernel) ----------------

__global__ __launch_bounds__(256) void zero_out_kernel(float4* __restrict__ out, int n4) {
    int i = blockIdx.x * blockDim.x + threadIdx.x;
    if (i < n4) out[i] = make_float4(0.f, 0.f, 0.f, 0.f);
}

__global__ __launch_bounds__(256) void atomic_conv_edge_kernel(
    const float* __restrict__ feat, const float* __restrict__ dist,
    const int* __restrict__ src, const int* __restrict__ dst,
    const float* __restrict__ cutoffs, const float* __restrict__ means,
    const float* __restrict__ scaling, const float* __restrict__ feats_use,
    float* __restrict__ out)
{
    int e = blockIdx.x * blockDim.x + threadIdx.x;
    if (e >= NE) return;
    float d = dist[e];
    int s = src[e];
    int v = dst[e];
    float fv = feat[s];
    int ty = 0;
#pragma unroll
    for (int t = 1; t < NT; ++t) if (fv == feats_use[t]) ty = t;
    float* o = out + (size_t)v * (NT * NK) + (size_t)ty * NK;
#pragma unroll
    for (int k = 0; k < NK; ++k) {
        float c = cutoffs[k], m = means[k], sc = scaling[k];
        float dm = d - m;
        float rbf = __expf(-sc * dm * dm);
        float cosv = 0.5f * (__cosf(PI_F * d / c) + 1.0f);
        float he = (d <= c) ? rbf * cosv : 0.0f;
        __hip_atomic_fetch_add(o + k, he, __ATOMIC_RELAXED, __HIP_MEMORY_SCOPE_AGENT);
    }
}

// ---------------- bucket-sort + owner-compute reduce path ----------------

__global__ __launch_bounds__(256) void zero_counts_kernel(int* __restrict__ p, int n) {
    int i = blockIdx.x * blockDim.x + threadIdx.x;
    if (i < n) p[i] = 0;
}

// per-chunk histogram with the EXACT same chunk->group mapping as scatter_kernel:
// chunk c covers edges [c*SCH, c*SCH+SCH), group g = c & 7.
__global__ __launch_bounds__(256) void hist_kernel(const int4* __restrict__ dst4,
                                                   int* __restrict__ counts) {
    __shared__ int h[NB];
    for (int i = threadIdx.x; i < NB; i += 256) h[i] = 0;
    __syncthreads();
    const int nqTot = NE / 4;                 // 800000 quads
    int q0 = blockIdx.x * (SCH / 4);          // 2048 quads per chunk
    int nq = nqTot - q0;
    if (nq > SCH / 4) nq = SCH / 4;
    for (int i = threadIdx.x; i < nq; i += 256) {
        int4 v = dst4[q0 + i];
        atomicAdd(&h[v.x >> 7], 1);
        atomicAdd(&h[v.y >> 7], 1);
        atomicAdd(&h[v.z >> 7], 1);
        atomicAdd(&h[v.w >> 7], 1);
    }
    __syncthreads();
    int g = blockIdx.x & (NG - 1);
    for (int i = threadIdx.x; i < NB; i += 256) {
        int c = h[i];
        if (c) atomicAdd(&counts[i * NG + g], c);
    }
}

__global__ __launch_bounds__(1024) void scan_kernel(const int* __restrict__ counts,
                                                    int* __restrict__ offsets,
                                                    int* __restrict__ cursors) {
    __shared__ int s[1024];
    const int CH = (NBG + 1023) / 1024;  // 7
    int t = threadIdx.x;
    int base = t * CH;
    int loc[CH];
    int sum = 0;
#pragma unroll
    for (int i = 0; i < CH; ++i) {
        int idx = base + i;
        int v = (idx < NBG) ? counts[idx] : 0;
        loc[i] = sum;
        sum += v;
    }
    s[t] = sum;
    __syncthreads();
#pragma unroll
    for (int off = 1; off < 1024; off <<= 1) {
        int v = (t >= off) ? s[t - off] : 0;
        __syncthreads();
        s[t] += v;
        __syncthreads();
    }
    int excl = (t > 0) ? s[t - 1] : 0;
#pragma unroll
    for (int i = 0; i < CH; ++i) {
        int idx = base + i;
        if (idx < NBG) {
            int o = excl + loc[i];
            offsets[idx] = o;
            cursors[idx] = o;
        }
    }
    if (t == 1023) offsets[NBG] = NE;
}

// block-aggregated scatter: one cursor atomic per (bucket, block) instead of per edge.
// chunk c covers edges [c*SCH, c*SCH+SCH), group g = c & 7 — MUST match hist_kernel.
__global__ __launch_bounds__(256) void scatter_kernel(
    const float* __restrict__ feat, const float* __restrict__ dist,
    const int* __restrict__ src, const int* __restrict__ dst,
    const float* __restrict__ feats_use,
    int* __restrict__ cursors, unsigned* __restrict__ payload)
{
    __shared__ unsigned pld[SCH];
    __shared__ unsigned short bkt[SCH];
    __shared__ int hist[NB];
    __shared__ int base[NB];

    int t = threadIdx.x;
    int g = blockIdx.x & (NG - 1);
    int chunkBase = blockIdx.x * SCH;
    int n = NE - chunkBase;
    if (n > SCH) n = SCH;

    float f1 = feats_use[1], f2 = feats_use[2], f3 = feats_use[3];

    for (int i = t; i < NB; i += 256) hist[i] = 0;
    __syncthreads();

    for (int i = t; i < n; i += 256) {
        int e = chunkBase + i;
        float d = dist[e];
        int s = src[e];
        int v = dst[e];
        float fv = feat[s];
        int ty = (fv == f1) ? 1 : (fv == f2) ? 2 : (fv == f3) ? 3 : 0;
        int b = v >> 7;
        // [31:9]=top 23 bits of d | [8:7]=ty | [6:0]=ldst
        unsigned packed = (__float_as_uint(d) & 0xFFFFFE00u) |
                          ((unsigned)ty << 7) | (unsigned)(v & 127);
        pld[i] = packed;
        bkt[i] = (unsigned short)b;
        atomicAdd(&hist[b], 1);
    }
    __syncthreads();

    for (int i = t; i < NB; i += 256) {
        int c = hist[i];
        base[i] = c ? __hip_atomic_fetch_add(&cursors[i * NG + g], c,
                                             __ATOMIC_RELAXED, __HIP_MEMORY_SCOPE_AGENT)
                    : 0;
        hist[i] = 0;  // reuse as block-local cursor
    }
    __syncthreads();

    for (int i = t; i < n; i += 256) {
        int b = bkt[i];
        int lp = atomicAdd(&hist[b], 1);
        payload[base[b] + lp] = pld[i];
    }
}

// one block per bucket: LDS counting sort by key=(ldst<<1)|ty_hi, then
// thread t owns key t -> register accumulation, no atomics in hot loop.
// R6-proven shell (BCAP 6016, 3 blocks/CU); only the inner math is new.
__global__ __launch_bounds__(256, 3) void reduce_kernel(
    const unsigned* __restrict__ payload, const int* __restrict__ offsets,
    const float* __restrict__ cutoffs, const float* __restrict__ means,
    const float* __restrict__ scaling, float* __restrict__ out)
{
    __shared__ unsigned raw[BCAP];
    __shared__ unsigned srt[BCAP];
    __shared__ int scn[256];
    __shared__ int cur[256];
    __shared__ int coff[257];

    int b = blockIdx.x;
    int t = threadIdx.x;
    int s0 = offsets[b * NG];
    int s1 = offsets[(b + 1) * NG];

    float m_[NK], nsc_[NK], c_[NK], w_[NK], c1_[NK];
    bool uniformC = true;
#pragma unroll
    for (int k = 0; k < NK; ++k) {
        m_[k] = means[k];
        nsc_[k] = -scaling[k];
        c_[k] = cutoffs[k];
        w_[k] = PI_F / cutoffs[k];
        c1_[k] = -scaling[k] * LOG2E_F;   // exp(-s x) == exp2(c1 x)
        uniformC = uniformC && (cutoffs[k] == cutoffs[0]);
    }
    float c0 = c_[0];
    float w0 = w_[0];

    float accA[NK], accB[NK];
#pragma unroll
    for (int k = 0; k < NK; ++k) { accA[k] = 0.f; accB[k] = 0.f; }

    for (int base = s0; base < s1; base += BCAP) {
        int n = s1 - base;
        if (n > BCAP) n = BCAP;

        for (int i = t; i < n; i += 256) raw[i] = payload[base + i];
        scn[t] = 0;
        __syncthreads();

        for (int i = t; i < n; i += 256) {
            unsigned p = raw[i];
            int key = ((p & 127) << 1) | ((p >> 8) & 1);
            atomicAdd(&scn[key], 1);
        }
        __syncthreads();

        int x = scn[t];
#pragma unroll
        for (int off2 = 1; off2 < 256; off2 <<= 1) {
            int v = (t >= off2) ? scn[t - off2] : 0;
            __syncthreads();
            scn[t] += v;
            __syncthreads();
        }
        int excl = scn[t] - x;
        coff[t] = excl;
        cur[t] = excl;
        if (t == 0) coff[256] = n;
        __syncthreads();

        for (int i = t; i < n; i += 256) {
            unsigned p = raw[i];
            int key = ((p & 127) << 1) | ((p >> 8) & 1);
            int pos = atomicAdd(&cur[key], 1);
            srt[pos] = p;
        }
        __syncthreads();

        int e0 = coff[t];
        int e1 = coff[t + 1];
        if (uniformC) {
            // fast path: single cos + cutoff per edge; 2-way unroll for exp ILP
#pragma unroll 2
            for (int i = e0; i < e1; ++i) {
                unsigned p = srt[i];
                float d = __uint_as_float(p & 0xFFFFFE00u);
                int typar = (p >> 7) & 1;
                float cv = 0.5f * (__cosf(w0 * d) + 1.0f);
                cv = (d <= c0) ? cv : 0.0f;
                float mA = typar ? 0.0f : cv;
                float mB = typar ? cv : 0.0f;
#pragma unroll
                for (int k = 0; k < NK; ++k) {
                    float dm = d - m_[k];
                    float e = exp2f(c1_[k] * (dm * dm));
                    accA[k] = fmaf(e, mA, accA[k]);
                    accB[k] = fmaf(e, mB, accB[k]);
                }
            }
        } else {
            // generic path
            for (int i = e0; i < e1; ++i) {
                unsigned p = srt[i];
                float d = __uint_as_float(p & 0xFFFFFE00u);
                int typar = (p >> 7) & 1;
                float he[NK];
#pragma unroll
                for (int k = 0; k < NK; ++k) {
                    float dm = d - m_[k];
                    float rbf = __expf(nsc_[k] * dm * dm);
                    float cosv = 0.5f * (__cosf(w_[k] * d) + 1.0f);
                    he[k] = (d <= c_[k]) ? rbf * cosv : 0.0f;
                }
                if (typar == 0) {
#pragma unroll
                    for (int k = 0; k < NK; ++k) accA[k] += he[k];
                } else {
#pragma unroll
                    for (int k = 0; k < NK; ++k) accB[k] += he[k];
                }
            }
        }
        __syncthreads();
    }

    int node = b * 128 + (t >> 1);
    if (node < NV) {
        int h = t & 1;
        float4* o = (float4*)(out + (size_t)node * 64 + h * 32);
#pragma unroll
        for (int k = 0; k < 4; ++k)
            o[k] = make_float4(accA[4 * k], accA[4 * k + 1], accA[4 * k + 2], accA[4 * k + 3]);
#pragma unroll
        for (int k = 0; k < 4; ++k)
            o[4 + k] = make_float4(accB[4 * k], accB[4 * k + 1], accB[4 * k + 2], accB[4 * k + 3]);
    }
}

extern "C" void kernel_launch(void* const* d_in, const int* in_sizes, int n_in,
                              void* d_out, int out_size, void* d_ws, size_t ws_size,
                              hipStream_t stream) {
    const float* feat      = (const float*)d_in[0];
    const float* dist      = (const float*)d_in[1];
    const int*   src       = (const int*)d_in[2];
    const int*   dst       = (const int*)d_in[3];
    const float* cutoffs   = (const float*)d_in[4];
    const float* means     = (const float*)d_in[5];
    const float* scaling   = (const float*)d_in[6];
    const float* feats_use = (const float*)d_in[7];
    float* out = (float*)d_out;

    size_t off = 0;
    auto alloc = [&](size_t bytes) {
        size_t cur = off;
        off = (off + bytes + 255) & ~(size_t)255;
        return cur;
    };
    size_t o_counts  = alloc((size_t)NBG * 4);
    size_t o_offsets = alloc((size_t)(NBG + 1) * 4);
    size_t o_cursors = alloc((size_t)NBG * 4);
    size_t o_payload = alloc((size_t)NE * 4);
    size_t needed = off;

    if (ws_size < needed) {
        int n4 = out_size / 4;
        zero_out_kernel<<<(n4 + 255) / 256, 256, 0, stream>>>((float4*)out, n4);
        atomic_conv_edge_kernel<<<(NE + 255) / 256, 256, 0, stream>>>(
            feat, dist, src, dst, cutoffs, means, scaling, feats_use, out);
        return;
    }

    char* ws = (char*)d_ws;
    int* counts  = (int*)(ws + o_counts);
    int* offsets = (int*)(ws + o_offsets);
    int* cursors = (int*)(ws + o_cursors);
    unsigned* payload = (unsigned*)(ws + o_payload);

    zero_counts_kernel<<<(NBG + 255) / 256, 256, 0, stream>>>(counts, NBG);

    hist_kernel<<<NCHUNK, 256, 0, stream>>>((const int4*)dst, counts);

    scan_kernel<<<1, 1024, 0, stream>>>(counts, offsets, cursors);

    scatter_kernel<<<NCHUNK, 256, 0, stream>>>(
        feat, dist, src, dst, feats_use, cursors, payload);

    reduce_kernel<<<NB, 256, 0, stream>>>(
        payload, offsets, cutoffs, means, scaling, out);
}